// Round 4
// baseline (52.707 us; speedup 1.0000x reference)
//
#include <hip/hip_runtime.h>

// Problem constants (setup_inputs: N=C=1, H=384, W=1248, maxdisp=128).
constexpr int H     = 384;
constexpr int W     = 1248;
constexpr int W4    = W / 4;    // 312 float4 positions per row
constexpr int DG    = 32;       // disparities per block
constexpr int BLOCK = 320;      // 5 waves; threads t<312 compute, rest idle
constexpr int LSHN  = 1392;     // W + pad: sliding window reads up to idx 1379

typedef float f32x4 __attribute__((ext_vector_type(4)));  // native vec for nt-store

__global__ __launch_bounds__(BLOCK) void hamming_cost_kernel(
    const int* __restrict__ left,
    const int* __restrict__ right,
    float* __restrict__ out,
    int ngroups)
{
    __shared__ __align__(16) int lsh[LSHN];

    const int bid = blockIdx.x;
    const int h   = bid / ngroups;
    const int d0  = (bid - h * ngroups) * DG;
    const int t   = threadIdx.x;

    const int* lrow = left  + h * W;
    const int* rrow = right + h * W;

    // Stage left row into LDS: 312 aligned int4 loads (pad left uninitialized —
    // any element with index >= W only ever feeds masked-to-zero outputs).
    if (t < W4)
        reinterpret_cast<int4*>(lsh)[t] = reinterpret_cast<const int4*>(lrow)[t];
    __syncthreads();

    if (t >= W4) return;

    const int x0 = 4 * t;
    // right stays in registers for all 32 disparities
    const int4 r = reinterpret_cast<const int4*>(rrow)[t];

    // Sliding 8-int window over left: A = left[x0+d .. +3], B = left[x0+d+4 .. +7],
    // valid while d % 4 == 0 (16B-aligned LDS reads).
    int4 A = *reinterpret_cast<const int4*>(&lsh[x0 + d0]);
    int4 B = *reinterpret_cast<const int4*>(&lsh[x0 + d0 + 4]);

    float* optr = out + ((size_t)d0 * H + h) * W + x0;
    const size_t dstride = (size_t)H * W;   // advance one disparity plane

    for (int dd = 0; dd < DG; dd += 4) {
        const int d = d0 + dd;
        int lim = W - d;   // lane i valid iff x0 + i < lim; decremented per sub-d

        f32x4 o;
        // j = 0: window A.x..A.w
        o.x = (x0     < lim) ? (float)__popc((unsigned)(A.x ^ r.x)) : 0.0f;
        o.y = (x0 + 1 < lim) ? (float)__popc((unsigned)(A.y ^ r.y)) : 0.0f;
        o.z = (x0 + 2 < lim) ? (float)__popc((unsigned)(A.z ^ r.z)) : 0.0f;
        o.w = (x0 + 3 < lim) ? (float)__popc((unsigned)(A.w ^ r.w)) : 0.0f;
        __builtin_nontemporal_store(o, reinterpret_cast<f32x4*>(optr));
        optr += dstride; --lim;

        // j = 1: A.y A.z A.w B.x
        o.x = (x0     < lim) ? (float)__popc((unsigned)(A.y ^ r.x)) : 0.0f;
        o.y = (x0 + 1 < lim) ? (float)__popc((unsigned)(A.z ^ r.y)) : 0.0f;
        o.z = (x0 + 2 < lim) ? (float)__popc((unsigned)(A.w ^ r.z)) : 0.0f;
        o.w = (x0 + 3 < lim) ? (float)__popc((unsigned)(B.x ^ r.w)) : 0.0f;
        __builtin_nontemporal_store(o, reinterpret_cast<f32x4*>(optr));
        optr += dstride; --lim;

        // j = 2: A.z A.w B.x B.y
        o.x = (x0     < lim) ? (float)__popc((unsigned)(A.z ^ r.x)) : 0.0f;
        o.y = (x0 + 1 < lim) ? (float)__popc((unsigned)(A.w ^ r.y)) : 0.0f;
        o.z = (x0 + 2 < lim) ? (float)__popc((unsigned)(B.x ^ r.z)) : 0.0f;
        o.w = (x0 + 3 < lim) ? (float)__popc((unsigned)(B.y ^ r.w)) : 0.0f;
        __builtin_nontemporal_store(o, reinterpret_cast<f32x4*>(optr));
        optr += dstride; --lim;

        // j = 3: A.w B.x B.y B.z
        o.x = (x0     < lim) ? (float)__popc((unsigned)(A.w ^ r.x)) : 0.0f;
        o.y = (x0 + 1 < lim) ? (float)__popc((unsigned)(B.x ^ r.y)) : 0.0f;
        o.z = (x0 + 2 < lim) ? (float)__popc((unsigned)(B.y ^ r.z)) : 0.0f;
        o.w = (x0 + 3 < lim) ? (float)__popc((unsigned)(B.z ^ r.w)) : 0.0f;
        __builtin_nontemporal_store(o, reinterpret_cast<f32x4*>(optr));
        optr += dstride;

        // slide window by 4
        A = B;
        B = *reinterpret_cast<const int4*>(&lsh[x0 + d + 8]);  // max idx 1379 < LSHN
    }
}

extern "C" void kernel_launch(void* const* d_in, const int* in_sizes, int n_in,
                              void* d_out, int out_size, void* d_ws, size_t ws_size,
                              hipStream_t stream)
{
    const int* left  = (const int*)d_in[0];
    const int* right = (const int*)d_in[1];
    float* out = (float*)d_out;

    const int maxdisp = out_size / (H * W);   // 128
    const int ngroups = maxdisp / DG;         // 4 (maxdisp is fixed at 128)
    const int grid    = H * ngroups;          // 1536 blocks = 6 blocks/CU exactly

    hipLaunchKernelGGL(hamming_cost_kernel, dim3(grid), dim3(BLOCK), 0, stream,
                       left, right, out, ngroups);
}

// Round 5
// 42.311 us; speedup vs baseline: 1.2457x; 1.2457x over previous
//
#include <hip/hip_runtime.h>

// Problem constants (setup_inputs: N=C=1, H=384, W=1248, maxdisp=128).
constexpr int H     = 384;
constexpr int W     = 1248;
constexpr int W4    = W / 4;    // 312 float4 positions per row
constexpr int DG    = 64;       // disparities per block
constexpr int BLOCK = 320;      // 5 waves; threads t<312 compute, rest idle
constexpr int LSHN  = 1392;     // W + pad: sliding window reads up to idx 1379

__global__ __launch_bounds__(BLOCK) void hamming_cost_kernel(
    const int* __restrict__ left,
    const int* __restrict__ right,
    float* __restrict__ out,
    int ngroups)
{
    __shared__ __align__(16) int lsh[LSHN];

    const int bid = blockIdx.x;
    const int h   = bid / ngroups;
    const int d0  = (bid - h * ngroups) * DG;
    const int t   = threadIdx.x;

    const int* lrow = left  + h * W;
    const int* rrow = right + h * W;

    // Stage left row into LDS: 312 aligned int4 loads (pad left uninitialized —
    // any element with index >= W only ever feeds masked-to-zero outputs).
    if (t < W4)
        reinterpret_cast<int4*>(lsh)[t] = reinterpret_cast<const int4*>(lrow)[t];
    __syncthreads();

    if (t >= W4) return;

    const int x0 = 4 * t;
    // right stays in registers for all DG disparities
    const int4 r = reinterpret_cast<const int4*>(rrow)[t];

    // Sliding 8-int window over left: A = left[x0+d .. +3], B = left[x0+d+4 .. +7],
    // 16B-aligned LDS reads since d % 4 == 0 at each reload point.
    int4 A = *reinterpret_cast<const int4*>(&lsh[x0 + d0]);
    int4 B = *reinterpret_cast<const int4*>(&lsh[x0 + d0 + 4]);

    float* optr = out + ((size_t)d0 * H + h) * W + x0;
    const size_t dstride = (size_t)H * W;   // advance one disparity plane

    for (int dd = 0; dd < DG; dd += 4) {
        const int d = d0 + dd;
        int lim = W - d;   // lane i valid iff x0 + i < lim; decremented per sub-d

        float4 o;
        // j = 0: window A.x..A.w
        o.x = (x0     < lim) ? (float)__popc((unsigned)(A.x ^ r.x)) : 0.0f;
        o.y = (x0 + 1 < lim) ? (float)__popc((unsigned)(A.y ^ r.y)) : 0.0f;
        o.z = (x0 + 2 < lim) ? (float)__popc((unsigned)(A.z ^ r.z)) : 0.0f;
        o.w = (x0 + 3 < lim) ? (float)__popc((unsigned)(A.w ^ r.w)) : 0.0f;
        *reinterpret_cast<float4*>(optr) = o;
        optr += dstride; --lim;

        // j = 1: A.y A.z A.w B.x
        o.x = (x0     < lim) ? (float)__popc((unsigned)(A.y ^ r.x)) : 0.0f;
        o.y = (x0 + 1 < lim) ? (float)__popc((unsigned)(A.z ^ r.y)) : 0.0f;
        o.z = (x0 + 2 < lim) ? (float)__popc((unsigned)(A.w ^ r.z)) : 0.0f;
        o.w = (x0 + 3 < lim) ? (float)__popc((unsigned)(B.x ^ r.w)) : 0.0f;
        *reinterpret_cast<float4*>(optr) = o;
        optr += dstride; --lim;

        // j = 2: A.z A.w B.x B.y
        o.x = (x0     < lim) ? (float)__popc((unsigned)(A.z ^ r.x)) : 0.0f;
        o.y = (x0 + 1 < lim) ? (float)__popc((unsigned)(A.w ^ r.y)) : 0.0f;
        o.z = (x0 + 2 < lim) ? (float)__popc((unsigned)(B.x ^ r.z)) : 0.0f;
        o.w = (x0 + 3 < lim) ? (float)__popc((unsigned)(B.y ^ r.w)) : 0.0f;
        *reinterpret_cast<float4*>(optr) = o;
        optr += dstride; --lim;

        // j = 3: A.w B.x B.y B.z
        o.x = (x0     < lim) ? (float)__popc((unsigned)(A.w ^ r.x)) : 0.0f;
        o.y = (x0 + 1 < lim) ? (float)__popc((unsigned)(B.x ^ r.y)) : 0.0f;
        o.z = (x0 + 2 < lim) ? (float)__popc((unsigned)(B.y ^ r.z)) : 0.0f;
        o.w = (x0 + 3 < lim) ? (float)__popc((unsigned)(B.z ^ r.w)) : 0.0f;
        *reinterpret_cast<float4*>(optr) = o;
        optr += dstride;

        // slide window by 4
        A = B;
        B = *reinterpret_cast<const int4*>(&lsh[x0 + d + 8]);  // max idx 1379 < LSHN
    }
}

extern "C" void kernel_launch(void* const* d_in, const int* in_sizes, int n_in,
                              void* d_out, int out_size, void* d_ws, size_t ws_size,
                              hipStream_t stream)
{
    const int* left  = (const int*)d_in[0];
    const int* right = (const int*)d_in[1];
    float* out = (float*)d_out;

    const int maxdisp = out_size / (H * W);   // 128
    const int ngroups = maxdisp / DG;         // 2
    const int grid    = H * ngroups;          // 768 blocks = 3 blocks/CU exactly

    hipLaunchKernelGGL(hamming_cost_kernel, dim3(grid), dim3(BLOCK), 0, stream,
                       left, right, out, ngroups);
}